// Round 10
// baseline (656.041 us; speedup 1.0000x reference)
//
#include <hip/hip_runtime.h>
#include <stdint.h>

// instant-ngp multilevel hash-grid encoding, MI355X.
//
// R2: one kernel: 700us, FETCH 2.04GB (16 tables thrash L2).
// R5: kernel-per-hash-level + staged merge: 681us (dense 253).
// R8: branchy paired loads: dense 285us (VGPR 112, occ 21%). REVERTED.
// R9: LDS-stage levels 0+1: dense 211us. Model confirmed: per-level cost is
//     VMEM address/request count, not line count, not residency.
// R10 (this):
//   (a) dense levels 2-7 read PACKED-PAIR tables built in d_ws each launch:
//       T2[i]=(T[i],T[i+1]) -> x-corner pair = ONE 16B gather, branch-free
//       (shift+clamp handles ix=-1 edge). 8 -> 4 gathers/point/level.
//   (b) hash kernels PPT=2 (two independent chains/thread) -> 2x outstanding
//       requests; tests latency-bound vs TA-issue-bound.

struct EmbPtrs { const float2* p[16]; };
struct PkPtrs  { const float4* p[6];  };   // packed tables for levels 2..7

constexpr int BLOCK  = 256;
constexpr int DBLOCK = 1024;
constexpr int L0N = 16*16*16;   // 32768 B in LDS
constexpr int L1N = 20*20*20;   // 64000 B in LDS
constexpr int kRes[16] = {16,20,25,32,40,50,64,80,101,128,161,203,256,322,406,512};
constexpr int kPkEnt[6] = {25*25*25, 32*32*32, 40*40*40, 50*50*50, 64*64*64, 80*80*80};
constexpr uint32_t P1 = 2654435761u, P2 = 805459861u;
constexpr uint32_t HMASK = (1u << 19) - 1u;

struct Tri {
    int ix, iy, iz;
    float wx[2], wy[2], wz[2];
    bool vx[2], vy[2], vz[2];
};

template<int RES_>
__device__ __forceinline__ Tri tri_setup(float px, float py, float pz)
{
    Tri s;
    const float rh = (float)RES_ * 0.5f;
    const float xp = (px + 1.0f) * rh - 0.5f;   // match reference op order
    const float yp = (py + 1.0f) * rh - 0.5f;
    const float zp = (pz + 1.0f) * rh - 0.5f;
    const float fx = floorf(xp), fy = floorf(yp), fz = floorf(zp);
    s.ix = (int)fx; s.iy = (int)fy; s.iz = (int)fz;
    const float tx = xp - fx, ty = yp - fy, tz = zp - fz;
    s.wx[0] = 1.0f - tx; s.wx[1] = tx;
    s.wy[0] = 1.0f - ty; s.wy[1] = ty;
    s.wz[0] = 1.0f - tz; s.wz[1] = tz;
    s.vx[0] = (s.ix   >= 0) && (s.ix   < RES_); s.vx[1] = (s.ix+1 >= 0) && (s.ix+1 < RES_);
    s.vy[0] = (s.iy   >= 0) && (s.iy   < RES_); s.vy[1] = (s.iy+1 >= 0) && (s.iy+1 < RES_);
    s.vz[0] = (s.iz   >= 0) && (s.iz   < RES_); s.vz[1] = (s.iz+1 >= 0) && (s.iz+1 < RES_);
    return s;
}

// simple 8-gather version (LDS or global ptr)
template<int RES_, typename PTR>
__device__ __forceinline__ float2 dense_feat(PTR tab, float px, float py, float pz)
{
    const Tri s = tri_setup<RES_>(px, py, pz);
    constexpr int r2 = RES_ * RES_;
    const int base = s.ix + s.iy * RES_ + s.iz * r2;
    float ax = 0.0f, ay = 0.0f;
#pragma unroll
    for (int k = 0; k < 2; ++k)
#pragma unroll
    for (int j = 0; j < 2; ++j)
#pragma unroll
    for (int i = 0; i < 2; ++i) {
        const bool v = s.vx[i] && s.vy[j] && s.vz[k];
        const uint32_t idx = v ? (uint32_t)(base + i + j*RES_ + k*r2) : 0u;
        const float w = v ? (s.wx[i]*s.wy[j]*s.wz[k]) : 0.0f;
        const float2 e = tab[idx];
        ax = fmaf(e.x, w, ax);
        ay = fmaf(e.y, w, ay);
    }
    return make_float2(ax, ay);
}

// packed-pair version: tab[i] = (T[i], T[i+1]); 4 gathers instead of 8.
template<int RES_>
__device__ __forceinline__ float2 dense_feat_pk(const float4* __restrict__ tab,
                                                float px, float py, float pz)
{
    const Tri s = tri_setup<RES_>(px, py, pz);
    constexpr int r2 = RES_ * RES_;
    constexpr int NE = RES_ * r2;
    const int shift = (s.ix < 0) ? 1 : 0;   // ix=-1: pair starts one later
    float ax = 0.0f, ay = 0.0f;
#pragma unroll
    for (int k = 0; k < 2; ++k)
#pragma unroll
    for (int j = 0; j < 2; ++j) {
        const bool vyz = s.vy[j] && s.vz[k];
        const float wyz = s.wy[j] * s.wz[k];
        const float w0 = (vyz && s.vx[0]) ? s.wx[0] * wyz : 0.0f;
        const float w1 = (vyz && s.vx[1]) ? s.wx[1] * wyz : 0.0f;
        int a = s.ix + shift + (s.iy + j) * RES_ + (s.iz + k) * r2;
        a = min(max(a, 0), NE - 1);          // safe for w=0 rows
        const float4 q = tab[a];             // (T[a], T[a+1])
        const float wA = shift ? w1 : w0;    // shift=1: q.lo is corner x1
        const float wB = shift ? 0.0f : w1;
        ax = fmaf(q.x, wA, ax); ay = fmaf(q.y, wA, ay);
        ax = fmaf(q.z, wB, ax); ay = fmaf(q.w, wB, ay);
    }
    return make_float2(ax, ay);
}

template<int RES_>
__device__ __forceinline__ float2 hash_feat(const float2* __restrict__ tab,
                                            float px, float py, float pz)
{
    const Tri s = tri_setup<RES_>(px, py, pz);
    const uint32_t hy0 = (uint32_t)s.iy * P1;
    const uint32_t hz0 = (uint32_t)s.iz * P2;
    const uint32_t hx[2] = {(uint32_t)s.ix, (uint32_t)s.ix + 1u};
    const uint32_t hy[2] = {hy0, hy0 + P1};
    const uint32_t hz[2] = {hz0, hz0 + P2};
    float ax = 0.0f, ay = 0.0f;
#pragma unroll
    for (int k = 0; k < 2; ++k)
#pragma unroll
    for (int j = 0; j < 2; ++j)
#pragma unroll
    for (int i = 0; i < 2; ++i) {
        const bool v = s.vx[i] && s.vy[j] && s.vz[k];
        uint32_t idx = (hx[i] ^ hy[j] ^ hz[k]) & HMASK;
        idx = v ? idx : 0u;
        const float w = v ? (s.wx[i]*s.wy[j]*s.wz[k]) : 0.0f;
        const float2 e = tab[idx];
        ax = fmaf(e.x, w, ax);
        ay = fmaf(e.y, w, ay);
    }
    return make_float2(ax, ay);
}

// ---- repack: r[i] = (t[i], t[min(i+1,NE-1)]) ----
template<int NE>
__global__ __launch_bounds__(BLOCK) void repack_kernel(
    const float2* __restrict__ t, float4* __restrict__ r)
{
    const int i = blockIdx.x * BLOCK + threadIdx.x;
    if (i >= NE) return;
    const float2 a = t[i];
    const float2 b = t[(i + 1 < NE) ? i + 1 : i];
    r[i] = make_float4(a.x, a.y, b.x, b.y);
}

// ---- Dense levels 0-7: L0,L1 from LDS; L2-7 packed-pair; lower 64B out ----
__global__ __launch_bounds__(DBLOCK) void dense_kernel_pk(
    const float* __restrict__ x, EmbPtrs embs, PkPtrs pk,
    float4* __restrict__ out, int n)
{
    __shared__ float2 lds0[L0N];
    __shared__ float2 lds1[L1N];
    {
        const float4* g0 = (const float4*)embs.p[0];
        const float4* g1 = (const float4*)embs.p[1];
        float4* s0 = (float4*)lds0;
        float4* s1 = (float4*)lds1;
#pragma unroll 2
        for (int i = threadIdx.x; i < L0N/2; i += DBLOCK) s0[i] = g0[i];
#pragma unroll 4
        for (int i = threadIdx.x; i < L1N/2; i += DBLOCK) s1[i] = g1[i];
    }
    __syncthreads();

    const int b = blockIdx.x * DBLOCK + threadIdx.x;
    if (b >= n) return;
    const float px = x[3*b+0], py = x[3*b+1], pz = x[3*b+2];

    float2 f[8];
    f[0] = dense_feat<16>((const float2*)lds0, px, py, pz);
    f[1] = dense_feat<20>((const float2*)lds1, px, py, pz);
    f[2] = dense_feat_pk<25>(pk.p[0], px, py, pz);
    f[3] = dense_feat_pk<32>(pk.p[1], px, py, pz);
    f[4] = dense_feat_pk<40>(pk.p[2], px, py, pz);
    f[5] = dense_feat_pk<50>(pk.p[3], px, py, pz);
    f[6] = dense_feat_pk<64>(pk.p[4], px, py, pz);
    f[7] = dense_feat_pk<80>(pk.p[5], px, py, pz);

    float4* o = out + (size_t)b * 8;
#pragma unroll
    for (int i = 0; i < 4; ++i)
        o[i] = make_float4(f[2*i].x, f[2*i].y, f[2*i+1].x, f[2*i+1].y);
}

// ---- R9 dense (no packed tables) for smaller ws ----
__global__ __launch_bounds__(DBLOCK) void dense_kernel(
    const float* __restrict__ x, EmbPtrs embs, float4* __restrict__ out, int n)
{
    __shared__ float2 lds0[L0N];
    __shared__ float2 lds1[L1N];
    {
        const float4* g0 = (const float4*)embs.p[0];
        const float4* g1 = (const float4*)embs.p[1];
        float4* s0 = (float4*)lds0;
        float4* s1 = (float4*)lds1;
#pragma unroll 2
        for (int i = threadIdx.x; i < L0N/2; i += DBLOCK) s0[i] = g0[i];
#pragma unroll 4
        for (int i = threadIdx.x; i < L1N/2; i += DBLOCK) s1[i] = g1[i];
    }
    __syncthreads();

    const int b = blockIdx.x * DBLOCK + threadIdx.x;
    if (b >= n) return;
    const float px = x[3*b+0], py = x[3*b+1], pz = x[3*b+2];

    float2 f[8];
    f[0] = dense_feat<16>((const float2*)lds0, px, py, pz);
    f[1] = dense_feat<20>((const float2*)lds1, px, py, pz);
    f[2] = dense_feat<25>(embs.p[2], px, py, pz);
    f[3] = dense_feat<32>(embs.p[3], px, py, pz);
    f[4] = dense_feat<40>(embs.p[4], px, py, pz);
    f[5] = dense_feat<50>(embs.p[5], px, py, pz);
    f[6] = dense_feat<64>(embs.p[6], px, py, pz);
    f[7] = dense_feat<80>(embs.p[7], px, py, pz);

    float4* o = out + (size_t)b * 8;
#pragma unroll
    for (int i = 0; i < 4; ++i)
        o[i] = make_float4(f[2*i].x, f[2*i].y, f[2*i+1].x, f[2*i+1].y);
}

// ---- One kernel per hash level, PPT=2 (two independent gather chains) ----
template<int L>
__global__ __launch_bounds__(BLOCK) void hash_level_kernel(
    const float* __restrict__ x, const float2* __restrict__ tab,
    float2* __restrict__ ws, int n)
{
    const int h = (n + 1) >> 1;
    const int b = blockIdx.x * BLOCK + threadIdx.x;
    if (b >= h) return;
    const int p1 = b + h;
    const int q1 = (p1 < n) ? p1 : b;       // clamp: compute unconditionally
    const float2 r0 = hash_feat<kRes[L]>(tab, x[3*b+0],  x[3*b+1],  x[3*b+2]);
    const float2 r1 = hash_feat<kRes[L]>(tab, x[3*q1+0], x[3*q1+1], x[3*q1+2]);
    ws[b] = r0;
    if (p1 < n) ws[p1] = r1;
}

// ---- Merge: 8 level-major streams -> upper 64B of each point ----
__global__ __launch_bounds__(BLOCK) void merge_kernel(
    const float2* __restrict__ ws, float4* __restrict__ out, int n)
{
    const int b = blockIdx.x * BLOCK + threadIdx.x;
    if (b >= n) return;
    float2 f[8];
#pragma unroll
    for (int l = 0; l < 8; ++l)
        f[l] = ws[(size_t)l * n + b];
    float4* o = out + (size_t)b * 8 + 4;
#pragma unroll
    for (int i = 0; i < 4; ++i)
        o[i] = make_float4(f[2*i].x, f[2*i].y, f[2*i+1].x, f[2*i+1].y);
}

// ---- Fallback if d_ws too small: single kernel, all levels ----
__global__ __launch_bounds__(BLOCK) void fallback_kernel(
    const float* __restrict__ x, EmbPtrs embs, float4* __restrict__ out, int n)
{
    const int b = blockIdx.x * BLOCK + threadIdx.x;
    if (b >= n) return;
    const float px = x[3*b+0], py = x[3*b+1], pz = x[3*b+2];
    float2 f[16];
    f[0]  = dense_feat<16 >(embs.p[0],  px, py, pz);
    f[1]  = dense_feat<20 >(embs.p[1],  px, py, pz);
    f[2]  = dense_feat<25 >(embs.p[2],  px, py, pz);
    f[3]  = dense_feat<32 >(embs.p[3],  px, py, pz);
    f[4]  = dense_feat<40 >(embs.p[4],  px, py, pz);
    f[5]  = dense_feat<50 >(embs.p[5],  px, py, pz);
    f[6]  = dense_feat<64 >(embs.p[6],  px, py, pz);
    f[7]  = dense_feat<80 >(embs.p[7],  px, py, pz);
    f[8]  = hash_feat<101>(embs.p[8],  px, py, pz);
    f[9]  = hash_feat<128>(embs.p[9],  px, py, pz);
    f[10] = hash_feat<161>(embs.p[10], px, py, pz);
    f[11] = hash_feat<203>(embs.p[11], px, py, pz);
    f[12] = hash_feat<256>(embs.p[12], px, py, pz);
    f[13] = hash_feat<322>(embs.p[13], px, py, pz);
    f[14] = hash_feat<406>(embs.p[14], px, py, pz);
    f[15] = hash_feat<512>(embs.p[15], px, py, pz);
    float4* o = out + (size_t)b * 8;
#pragma unroll
    for (int i = 0; i < 8; ++i)
        o[i] = make_float4(f[2*i].x, f[2*i].y, f[2*i+1].x, f[2*i+1].y);
}

extern "C" void kernel_launch(void* const* d_in, const int* in_sizes, int n_in,
                              void* d_out, int out_size, void* d_ws, size_t ws_size,
                              hipStream_t stream) {
    const float* x = (const float*)d_in[0];
    EmbPtrs embs;
    for (int l = 0; l < 16; ++l) embs.p[l] = (const float2*)d_in[1 + l];
    const int n = in_sizes[0] / 3;          // (B,3) fp32
    const int grid  = (n + BLOCK - 1) / BLOCK;
    const int hgrid = (((n + 1) >> 1) + BLOCK - 1) / BLOCK;
    const int dgrid = (n + DBLOCK - 1) / DBLOCK;
    float4* out = (float4*)d_out;

    const size_t hashBytes = (size_t)8 * (size_t)n * sizeof(float2);  // 64 MB @ 1M
    size_t pkBytes = 0;
    for (int i = 0; i < 6; ++i) pkBytes += (size_t)kPkEnt[i] * sizeof(float4);

    if (ws_size >= hashBytes + pkBytes) {
        float2* ws = (float2*)d_ws;
        // packed tables live after the hash staging area
        char* base = (char*)d_ws + hashBytes;
        float4* pkp[6];
        size_t off = 0;
        for (int i = 0; i < 6; ++i) { pkp[i] = (float4*)(base + off); off += (size_t)kPkEnt[i] * sizeof(float4); }
        PkPtrs pk; for (int i = 0; i < 6; ++i) pk.p[i] = pkp[i];

        repack_kernel<kPkEnt[0]><<<(kPkEnt[0]+BLOCK-1)/BLOCK, BLOCK, 0, stream>>>(embs.p[2], pkp[0]);
        repack_kernel<kPkEnt[1]><<<(kPkEnt[1]+BLOCK-1)/BLOCK, BLOCK, 0, stream>>>(embs.p[3], pkp[1]);
        repack_kernel<kPkEnt[2]><<<(kPkEnt[2]+BLOCK-1)/BLOCK, BLOCK, 0, stream>>>(embs.p[4], pkp[2]);
        repack_kernel<kPkEnt[3]><<<(kPkEnt[3]+BLOCK-1)/BLOCK, BLOCK, 0, stream>>>(embs.p[5], pkp[3]);
        repack_kernel<kPkEnt[4]><<<(kPkEnt[4]+BLOCK-1)/BLOCK, BLOCK, 0, stream>>>(embs.p[6], pkp[4]);
        repack_kernel<kPkEnt[5]><<<(kPkEnt[5]+BLOCK-1)/BLOCK, BLOCK, 0, stream>>>(embs.p[7], pkp[5]);

        dense_kernel_pk<<<dgrid, DBLOCK, 0, stream>>>(x, embs, pk, out, n);
        hash_level_kernel< 8><<<hgrid, BLOCK, 0, stream>>>(x, embs.p[ 8], ws + 0*(size_t)n, n);
        hash_level_kernel< 9><<<hgrid, BLOCK, 0, stream>>>(x, embs.p[ 9], ws + 1*(size_t)n, n);
        hash_level_kernel<10><<<hgrid, BLOCK, 0, stream>>>(x, embs.p[10], ws + 2*(size_t)n, n);
        hash_level_kernel<11><<<hgrid, BLOCK, 0, stream>>>(x, embs.p[11], ws + 3*(size_t)n, n);
        hash_level_kernel<12><<<hgrid, BLOCK, 0, stream>>>(x, embs.p[12], ws + 4*(size_t)n, n);
        hash_level_kernel<13><<<hgrid, BLOCK, 0, stream>>>(x, embs.p[13], ws + 5*(size_t)n, n);
        hash_level_kernel<14><<<hgrid, BLOCK, 0, stream>>>(x, embs.p[14], ws + 6*(size_t)n, n);
        hash_level_kernel<15><<<hgrid, BLOCK, 0, stream>>>(x, embs.p[15], ws + 7*(size_t)n, n);
        merge_kernel<<<grid, BLOCK, 0, stream>>>(ws, out, n);
    } else if (ws_size >= hashBytes) {
        float2* ws = (float2*)d_ws;
        dense_kernel<<<dgrid, DBLOCK, 0, stream>>>(x, embs, out, n);
        hash_level_kernel< 8><<<hgrid, BLOCK, 0, stream>>>(x, embs.p[ 8], ws + 0*(size_t)n, n);
        hash_level_kernel< 9><<<hgrid, BLOCK, 0, stream>>>(x, embs.p[ 9], ws + 1*(size_t)n, n);
        hash_level_kernel<10><<<hgrid, BLOCK, 0, stream>>>(x, embs.p[10], ws + 2*(size_t)n, n);
        hash_level_kernel<11><<<hgrid, BLOCK, 0, stream>>>(x, embs.p[11], ws + 3*(size_t)n, n);
        hash_level_kernel<12><<<hgrid, BLOCK, 0, stream>>>(x, embs.p[12], ws + 4*(size_t)n, n);
        hash_level_kernel<13><<<hgrid, BLOCK, 0, stream>>>(x, embs.p[13], ws + 5*(size_t)n, n);
        hash_level_kernel<14><<<hgrid, BLOCK, 0, stream>>>(x, embs.p[14], ws + 6*(size_t)n, n);
        hash_level_kernel<15><<<hgrid, BLOCK, 0, stream>>>(x, embs.p[15], ws + 7*(size_t)n, n);
        merge_kernel<<<grid, BLOCK, 0, stream>>>(ws, out, n);
    } else {
        fallback_kernel<<<grid, BLOCK, 0, stream>>>(x, embs, out, n);
    }
}

// Round 11
// 644.965 us; speedup vs baseline: 1.0172x; 1.0172x over previous
//
#include <hip/hip_runtime.h>
#include <stdint.h>

// instant-ngp multilevel hash-grid encoding, MI355X.
//
// Model (R2..R10, counter-validated): cost = unique random 64B lines serviced,
// ~4 CU-cycles/line, invariant to instruction count (R10 pk: 8->4 gathers, no
// change), MLP (PPT=2 null), and residency/FETCH (R2 2GB vs R5 0.4GB, same
// per-level cost). Levers that work: LDS-serve (R9: -21us/level) and L1-serve.
// R11: Morton-bin points (32^3) and run the DENSE kernel in bin order.
// DBLOCK=1024 + 94.5KB LDS => 1 block/CU => block owns all of L1; a 1024-pt
// Morton bucket spans ~8^3 cells at res 80 => per-level working set 50-200
// lines => levels 2-7 become L1 hits. Hash levels NOT binned (8 blocks/CU
// share L1 -> dilution): keep proven R9 form. Dense writes scattered full-64B
// sectors (no RMW). Repack/PPT2 (R10) reverted.

struct EmbPtrs { const float2* p[16]; };

constexpr int BLOCK  = 256;
constexpr int DBLOCK = 1024;
constexpr int L0N = 16*16*16;   // 32768 B in LDS
constexpr int L1N = 20*20*20;   // 64000 B in LDS
constexpr int NBINS = 32768;    // 32^3 Morton bins
constexpr int kRes[16] = {16,20,25,32,40,50,64,80,101,128,161,203,256,322,406,512};
constexpr uint32_t P1 = 2654435761u, P2 = 805459861u;
constexpr uint32_t HMASK = (1u << 19) - 1u;

struct Tri {
    int ix, iy, iz;
    float wx[2], wy[2], wz[2];
    bool vx[2], vy[2], vz[2];
};

template<int RES_>
__device__ __forceinline__ Tri tri_setup(float px, float py, float pz)
{
    Tri s;
    const float rh = (float)RES_ * 0.5f;
    const float xp = (px + 1.0f) * rh - 0.5f;   // match reference op order
    const float yp = (py + 1.0f) * rh - 0.5f;
    const float zp = (pz + 1.0f) * rh - 0.5f;
    const float fx = floorf(xp), fy = floorf(yp), fz = floorf(zp);
    s.ix = (int)fx; s.iy = (int)fy; s.iz = (int)fz;
    const float tx = xp - fx, ty = yp - fy, tz = zp - fz;
    s.wx[0] = 1.0f - tx; s.wx[1] = tx;
    s.wy[0] = 1.0f - ty; s.wy[1] = ty;
    s.wz[0] = 1.0f - tz; s.wz[1] = tz;
    s.vx[0] = (s.ix   >= 0) && (s.ix   < RES_); s.vx[1] = (s.ix+1 >= 0) && (s.ix+1 < RES_);
    s.vy[0] = (s.iy   >= 0) && (s.iy   < RES_); s.vy[1] = (s.iy+1 >= 0) && (s.iy+1 < RES_);
    s.vz[0] = (s.iz   >= 0) && (s.iz   < RES_); s.vz[1] = (s.iz+1 >= 0) && (s.iz+1 < RES_);
    return s;
}

template<int RES_, typename PTR>
__device__ __forceinline__ float2 dense_feat(PTR tab, float px, float py, float pz)
{
    const Tri s = tri_setup<RES_>(px, py, pz);
    constexpr int r2 = RES_ * RES_;
    const int base = s.ix + s.iy * RES_ + s.iz * r2;
    float ax = 0.0f, ay = 0.0f;
#pragma unroll
    for (int k = 0; k < 2; ++k)
#pragma unroll
    for (int j = 0; j < 2; ++j)
#pragma unroll
    for (int i = 0; i < 2; ++i) {
        const bool v = s.vx[i] && s.vy[j] && s.vz[k];
        const uint32_t idx = v ? (uint32_t)(base + i + j*RES_ + k*r2) : 0u;
        const float w = v ? (s.wx[i]*s.wy[j]*s.wz[k]) : 0.0f;
        const float2 e = tab[idx];
        ax = fmaf(e.x, w, ax);
        ay = fmaf(e.y, w, ay);
    }
    return make_float2(ax, ay);
}

template<int RES_>
__device__ __forceinline__ float2 hash_feat(const float2* __restrict__ tab,
                                            float px, float py, float pz)
{
    const Tri s = tri_setup<RES_>(px, py, pz);
    const uint32_t hy0 = (uint32_t)s.iy * P1;
    const uint32_t hz0 = (uint32_t)s.iz * P2;
    const uint32_t hx[2] = {(uint32_t)s.ix, (uint32_t)s.ix + 1u};
    const uint32_t hy[2] = {hy0, hy0 + P1};
    const uint32_t hz[2] = {hz0, hz0 + P2};
    float ax = 0.0f, ay = 0.0f;
#pragma unroll
    for (int k = 0; k < 2; ++k)
#pragma unroll
    for (int j = 0; j < 2; ++j)
#pragma unroll
    for (int i = 0; i < 2; ++i) {
        const bool v = s.vx[i] && s.vy[j] && s.vz[k];
        uint32_t idx = (hx[i] ^ hy[j] ^ hz[k]) & HMASK;
        idx = v ? idx : 0u;
        const float w = v ? (s.wx[i]*s.wy[j]*s.wz[k]) : 0.0f;
        const float2 e = tab[idx];
        ax = fmaf(e.x, w, ax);
        ay = fmaf(e.y, w, ay);
    }
    return make_float2(ax, ay);
}

// ---------------- binning ----------------
__device__ __forceinline__ uint32_t part1by2(uint32_t v)
{
    v = (v | (v << 16)) & 0x030000FFu;
    v = (v | (v << 8))  & 0x0300F00Fu;
    v = (v | (v << 4))  & 0x030C30C3u;
    v = (v | (v << 2))  & 0x09249249u;
    return v;
}

__device__ __forceinline__ uint32_t bin_of(float x, float y, float z)
{
    const int bx = min(max((int)((x + 1.0f) * 16.0f), 0), 31);
    const int by = min(max((int)((y + 1.0f) * 16.0f), 0), 31);
    const int bz = min(max((int)((z + 1.0f) * 16.0f), 0), 31);
    return part1by2((uint32_t)bx) | (part1by2((uint32_t)by) << 1) | (part1by2((uint32_t)bz) << 2);
}

__global__ __launch_bounds__(BLOCK) void hist_kernel(
    const float* __restrict__ x, uint32_t* __restrict__ hist, int n)
{
    const int b = blockIdx.x * BLOCK + threadIdx.x;
    if (b >= n) return;
    atomicAdd(&hist[bin_of(x[3*b+0], x[3*b+1], x[3*b+2])], 1u);
}

__global__ __launch_bounds__(1024) void scan_kernel(
    const uint32_t* __restrict__ hist, uint32_t* __restrict__ cursor)
{
    __shared__ uint32_t tot[1024];
    const int t = threadIdx.x;
    uint32_t v[32];
    uint32_t s = 0;
#pragma unroll
    for (int i = 0; i < 32; ++i) { v[i] = s; s += hist[t*32 + i]; }  // local exclusive
    tot[t] = s;
    __syncthreads();
    // Hillis-Steele inclusive scan of per-thread totals
    for (int off = 1; off < 1024; off <<= 1) {
        const uint32_t y = (t >= off) ? tot[t - off] : 0u;
        __syncthreads();
        tot[t] += y;
        __syncthreads();
    }
    const uint32_t base = tot[t] - s;   // exclusive
#pragma unroll
    for (int i = 0; i < 32; ++i) cursor[t*32 + i] = base + v[i];
}

__global__ __launch_bounds__(BLOCK) void scatter_kernel(
    const float* __restrict__ x, uint32_t* __restrict__ cursor,
    float4* __restrict__ xs, int n)
{
    const int b = blockIdx.x * BLOCK + threadIdx.x;
    if (b >= n) return;
    const float px = x[3*b+0], py = x[3*b+1], pz = x[3*b+2];
    const uint32_t pos = atomicAdd(&cursor[bin_of(px, py, pz)], 1u);
    xs[pos] = make_float4(px, py, pz, __int_as_float(b));
}

// ---- Dense levels 0-7, BIN ORDER: L0,L1 from LDS; out write scattered 64B ----
__global__ __launch_bounds__(DBLOCK) void dense_kernel_binned(
    const float4* __restrict__ xs, EmbPtrs embs, float4* __restrict__ out, int n)
{
    __shared__ float2 lds0[L0N];
    __shared__ float2 lds1[L1N];
    {
        const float4* g0 = (const float4*)embs.p[0];
        const float4* g1 = (const float4*)embs.p[1];
        float4* s0 = (float4*)lds0;
        float4* s1 = (float4*)lds1;
#pragma unroll 2
        for (int i = threadIdx.x; i < L0N/2; i += DBLOCK) s0[i] = g0[i];
#pragma unroll 4
        for (int i = threadIdx.x; i < L1N/2; i += DBLOCK) s1[i] = g1[i];
    }
    __syncthreads();

    const int i = blockIdx.x * DBLOCK + threadIdx.x;
    if (i >= n) return;
    const float4 q = xs[i];                       // coalesced
    const float px = q.x, py = q.y, pz = q.z;
    const int idx = __float_as_int(q.w);

    float2 f[8];
    f[0] = dense_feat<16>((const float2*)lds0, px, py, pz);
    f[1] = dense_feat<20>((const float2*)lds1, px, py, pz);
    f[2] = dense_feat<25>(embs.p[2], px, py, pz);
    f[3] = dense_feat<32>(embs.p[3], px, py, pz);
    f[4] = dense_feat<40>(embs.p[4], px, py, pz);
    f[5] = dense_feat<50>(embs.p[5], px, py, pz);
    f[6] = dense_feat<64>(embs.p[6], px, py, pz);
    f[7] = dense_feat<80>(embs.p[7], px, py, pz);

    float4* o = out + (size_t)idx * 8;            // scattered, full 64B sector
#pragma unroll
    for (int k = 0; k < 4; ++k)
        o[k] = make_float4(f[2*k].x, f[2*k].y, f[2*k+1].x, f[2*k+1].y);
}

// ---- R9 dense (original order) for reduced-ws fallback path ----
__global__ __launch_bounds__(DBLOCK) void dense_kernel(
    const float* __restrict__ x, EmbPtrs embs, float4* __restrict__ out, int n)
{
    __shared__ float2 lds0[L0N];
    __shared__ float2 lds1[L1N];
    {
        const float4* g0 = (const float4*)embs.p[0];
        const float4* g1 = (const float4*)embs.p[1];
        float4* s0 = (float4*)lds0;
        float4* s1 = (float4*)lds1;
#pragma unroll 2
        for (int i = threadIdx.x; i < L0N/2; i += DBLOCK) s0[i] = g0[i];
#pragma unroll 4
        for (int i = threadIdx.x; i < L1N/2; i += DBLOCK) s1[i] = g1[i];
    }
    __syncthreads();

    const int b = blockIdx.x * DBLOCK + threadIdx.x;
    if (b >= n) return;
    const float px = x[3*b+0], py = x[3*b+1], pz = x[3*b+2];

    float2 f[8];
    f[0] = dense_feat<16>((const float2*)lds0, px, py, pz);
    f[1] = dense_feat<20>((const float2*)lds1, px, py, pz);
    f[2] = dense_feat<25>(embs.p[2], px, py, pz);
    f[3] = dense_feat<32>(embs.p[3], px, py, pz);
    f[4] = dense_feat<40>(embs.p[4], px, py, pz);
    f[5] = dense_feat<50>(embs.p[5], px, py, pz);
    f[6] = dense_feat<64>(embs.p[6], px, py, pz);
    f[7] = dense_feat<80>(embs.p[7], px, py, pz);

    float4* o = out + (size_t)b * 8;
#pragma unroll
    for (int i = 0; i < 4; ++i)
        o[i] = make_float4(f[2*i].x, f[2*i].y, f[2*i+1].x, f[2*i+1].y);
}

// ---- One kernel per hash level (R9 proven form, original order) ----
template<int L>
__global__ __launch_bounds__(BLOCK) void hash_level_kernel(
    const float* __restrict__ x, const float2* __restrict__ tab,
    float2* __restrict__ ws, int n)
{
    const int b = blockIdx.x * BLOCK + threadIdx.x;
    if (b >= n) return;
    ws[b] = hash_feat<kRes[L]>(tab, x[3*b+0], x[3*b+1], x[3*b+2]);
}

// ---- Merge: 8 level-major streams -> upper 64B of each point ----
__global__ __launch_bounds__(BLOCK) void merge_kernel(
    const float2* __restrict__ ws, float4* __restrict__ out, int n)
{
    const int b = blockIdx.x * BLOCK + threadIdx.x;
    if (b >= n) return;
    float2 f[8];
#pragma unroll
    for (int l = 0; l < 8; ++l)
        f[l] = ws[(size_t)l * n + b];
    float4* o = out + (size_t)b * 8 + 4;
#pragma unroll
    for (int i = 0; i < 4; ++i)
        o[i] = make_float4(f[2*i].x, f[2*i].y, f[2*i+1].x, f[2*i+1].y);
}

// ---- Fallback if d_ws too small: single fused kernel ----
__global__ __launch_bounds__(BLOCK) void fallback_kernel(
    const float* __restrict__ x, EmbPtrs embs, float4* __restrict__ out, int n)
{
    const int b = blockIdx.x * BLOCK + threadIdx.x;
    if (b >= n) return;
    const float px = x[3*b+0], py = x[3*b+1], pz = x[3*b+2];
    float2 f[16];
    f[0]  = dense_feat<16 >(embs.p[0],  px, py, pz);
    f[1]  = dense_feat<20 >(embs.p[1],  px, py, pz);
    f[2]  = dense_feat<25 >(embs.p[2],  px, py, pz);
    f[3]  = dense_feat<32 >(embs.p[3],  px, py, pz);
    f[4]  = dense_feat<40 >(embs.p[4],  px, py, pz);
    f[5]  = dense_feat<50 >(embs.p[5],  px, py, pz);
    f[6]  = dense_feat<64 >(embs.p[6],  px, py, pz);
    f[7]  = dense_feat<80 >(embs.p[7],  px, py, pz);
    f[8]  = hash_feat<101>(embs.p[8],  px, py, pz);
    f[9]  = hash_feat<128>(embs.p[9],  px, py, pz);
    f[10] = hash_feat<161>(embs.p[10], px, py, pz);
    f[11] = hash_feat<203>(embs.p[11], px, py, pz);
    f[12] = hash_feat<256>(embs.p[12], px, py, pz);
    f[13] = hash_feat<322>(embs.p[13], px, py, pz);
    f[14] = hash_feat<406>(embs.p[14], px, py, pz);
    f[15] = hash_feat<512>(embs.p[15], px, py, pz);
    float4* o = out + (size_t)b * 8;
#pragma unroll
    for (int i = 0; i < 8; ++i)
        o[i] = make_float4(f[2*i].x, f[2*i].y, f[2*i+1].x, f[2*i+1].y);
}

extern "C" void kernel_launch(void* const* d_in, const int* in_sizes, int n_in,
                              void* d_out, int out_size, void* d_ws, size_t ws_size,
                              hipStream_t stream) {
    const float* x = (const float*)d_in[0];
    EmbPtrs embs;
    for (int l = 0; l < 16; ++l) embs.p[l] = (const float2*)d_in[1 + l];
    const int n = in_sizes[0] / 3;          // (B,3) fp32
    const int grid  = (n + BLOCK - 1) / BLOCK;
    const int dgrid = (n + DBLOCK - 1) / DBLOCK;
    float4* out = (float4*)d_out;

    // ws layout: [streams 8*n*8B][xs n*16B][hist 128KB][cursor 128KB]
    const size_t streamsB = (size_t)8 * (size_t)n * sizeof(float2);
    const size_t xsB      = (size_t)n * sizeof(float4);
    const size_t histB    = (size_t)NBINS * sizeof(uint32_t);
    const size_t needBin  = streamsB + xsB + 2 * histB;
    const size_t needR9   = streamsB;

    if (ws_size >= needBin) {
        float2*   ws     = (float2*)d_ws;
        float4*   xs     = (float4*)((char*)d_ws + streamsB);
        uint32_t* hist   = (uint32_t*)((char*)d_ws + streamsB + xsB);
        uint32_t* cursor = hist + NBINS;

        hipMemsetAsync(hist, 0, histB, stream);
        hist_kernel<<<grid, BLOCK, 0, stream>>>(x, hist, n);
        scan_kernel<<<1, 1024, 0, stream>>>(hist, cursor);
        scatter_kernel<<<grid, BLOCK, 0, stream>>>(x, cursor, xs, n);

        dense_kernel_binned<<<dgrid, DBLOCK, 0, stream>>>(xs, embs, out, n);
        hash_level_kernel< 8><<<grid, BLOCK, 0, stream>>>(x, embs.p[ 8], ws + 0*(size_t)n, n);
        hash_level_kernel< 9><<<grid, BLOCK, 0, stream>>>(x, embs.p[ 9], ws + 1*(size_t)n, n);
        hash_level_kernel<10><<<grid, BLOCK, 0, stream>>>(x, embs.p[10], ws + 2*(size_t)n, n);
        hash_level_kernel<11><<<grid, BLOCK, 0, stream>>>(x, embs.p[11], ws + 3*(size_t)n, n);
        hash_level_kernel<12><<<grid, BLOCK, 0, stream>>>(x, embs.p[12], ws + 4*(size_t)n, n);
        hash_level_kernel<13><<<grid, BLOCK, 0, stream>>>(x, embs.p[13], ws + 5*(size_t)n, n);
        hash_level_kernel<14><<<grid, BLOCK, 0, stream>>>(x, embs.p[14], ws + 6*(size_t)n, n);
        hash_level_kernel<15><<<grid, BLOCK, 0, stream>>>(x, embs.p[15], ws + 7*(size_t)n, n);
        merge_kernel<<<grid, BLOCK, 0, stream>>>(ws, out, n);
    } else if (ws_size >= needR9) {
        float2* ws = (float2*)d_ws;
        dense_kernel<<<dgrid, DBLOCK, 0, stream>>>(x, embs, out, n);
        hash_level_kernel< 8><<<grid, BLOCK, 0, stream>>>(x, embs.p[ 8], ws + 0*(size_t)n, n);
        hash_level_kernel< 9><<<grid, BLOCK, 0, stream>>>(x, embs.p[ 9], ws + 1*(size_t)n, n);
        hash_level_kernel<10><<<grid, BLOCK, 0, stream>>>(x, embs.p[10], ws + 2*(size_t)n, n);
        hash_level_kernel<11><<<grid, BLOCK, 0, stream>>>(x, embs.p[11], ws + 3*(size_t)n, n);
        hash_level_kernel<12><<<grid, BLOCK, 0, stream>>>(x, embs.p[12], ws + 4*(size_t)n, n);
        hash_level_kernel<13><<<grid, BLOCK, 0, stream>>>(x, embs.p[13], ws + 5*(size_t)n, n);
        hash_level_kernel<14><<<grid, BLOCK, 0, stream>>>(x, embs.p[14], ws + 6*(size_t)n, n);
        hash_level_kernel<15><<<grid, BLOCK, 0, stream>>>(x, embs.p[15], ws + 7*(size_t)n, n);
        merge_kernel<<<grid, BLOCK, 0, stream>>>(ws, out, n);
    } else {
        fallback_kernel<<<grid, BLOCK, 0, stream>>>(x, embs, out, n);
    }
}

// Round 13
// 612.348 us; speedup vs baseline: 1.0714x; 1.0533x over previous
//
#include <hip/hip_runtime.h>
#include <stdint.h>

// instant-ngp multilevel hash-grid encoding, MI355X.
//
// Cost model (R2..R11, counter-validated): runtime = unique 64B lines serviced
// per wave-gather, ~4 CU-cyc/line (TA rate). Invariant to: instruction count
// (R10), MLP (R10), L2 residency/FETCH (R2/R5/R10). Reducible by: LDS-serve
// (R9), and wave-level line dedup via Morton-sorted points (R11: dense 211->
// <99us). R12: (a) hash levels consume SORTED xs too (dedup at res 101-203),
// (b) all 8 hash levels fused into ONE kernel writing out[idx] upper 64B
// directly -- merge kernel and 64MB ws streams deleted (phasing proven
// irrelevant: per-level cost independent of residency).

struct EmbPtrs { const float2* p[16]; };

constexpr int BLOCK  = 256;
constexpr int DBLOCK = 1024;
constexpr int L0N = 16*16*16;   // 32768 B in LDS
constexpr int L1N = 20*20*20;   // 64000 B in LDS
constexpr int NBINS = 32768;    // 32^3 Morton bins
constexpr int kRes[16] = {16,20,25,32,40,50,64,80,101,128,161,203,256,322,406,512};
constexpr uint32_t P1 = 2654435761u, P2 = 805459861u;
constexpr uint32_t HMASK = (1u << 19) - 1u;

struct Tri {
    int ix, iy, iz;
    float wx[2], wy[2], wz[2];
    bool vx[2], vy[2], vz[2];
};

template<int RES_>
__device__ __forceinline__ Tri tri_setup(float px, float py, float pz)
{
    Tri s;
    const float rh = (float)RES_ * 0.5f;
    const float xp = (px + 1.0f) * rh - 0.5f;   // match reference op order
    const float yp = (py + 1.0f) * rh - 0.5f;
    const float zp = (pz + 1.0f) * rh - 0.5f;
    const float fx = floorf(xp), fy = floorf(yp), fz = floorf(zp);
    s.ix = (int)fx; s.iy = (int)fy; s.iz = (int)fz;
    const float tx = xp - fx, ty = yp - fy, tz = zp - fz;
    s.wx[0] = 1.0f - tx; s.wx[1] = tx;
    s.wy[0] = 1.0f - ty; s.wy[1] = ty;
    s.wz[0] = 1.0f - tz; s.wz[1] = tz;
    s.vx[0] = (s.ix   >= 0) && (s.ix   < RES_); s.vx[1] = (s.ix+1 >= 0) && (s.ix+1 < RES_);
    s.vy[0] = (s.iy   >= 0) && (s.iy   < RES_); s.vy[1] = (s.iy+1 >= 0) && (s.iy+1 < RES_);
    s.vz[0] = (s.iz   >= 0) && (s.iz   < RES_); s.vz[1] = (s.iz+1 >= 0) && (s.iz+1 < RES_);
    return s;
}

template<int RES_, typename PTR>
__device__ __forceinline__ float2 dense_feat(PTR tab, float px, float py, float pz)
{
    const Tri s = tri_setup<RES_>(px, py, pz);
    constexpr int r2 = RES_ * RES_;
    const int base = s.ix + s.iy * RES_ + s.iz * r2;
    float ax = 0.0f, ay = 0.0f;
#pragma unroll
    for (int k = 0; k < 2; ++k)
#pragma unroll
    for (int j = 0; j < 2; ++j)
#pragma unroll
    for (int i = 0; i < 2; ++i) {
        const bool v = s.vx[i] && s.vy[j] && s.vz[k];
        const uint32_t idx = v ? (uint32_t)(base + i + j*RES_ + k*r2) : 0u;
        const float w = v ? (s.wx[i]*s.wy[j]*s.wz[k]) : 0.0f;
        const float2 e = tab[idx];
        ax = fmaf(e.x, w, ax);
        ay = fmaf(e.y, w, ay);
    }
    return make_float2(ax, ay);
}

template<int RES_>
__device__ __forceinline__ float2 hash_feat(const float2* __restrict__ tab,
                                            float px, float py, float pz)
{
    const Tri s = tri_setup<RES_>(px, py, pz);
    const uint32_t hy0 = (uint32_t)s.iy * P1;
    const uint32_t hz0 = (uint32_t)s.iz * P2;
    const uint32_t hx[2] = {(uint32_t)s.ix, (uint32_t)s.ix + 1u};
    const uint32_t hy[2] = {hy0, hy0 + P1};
    const uint32_t hz[2] = {hz0, hz0 + P2};
    float ax = 0.0f, ay = 0.0f;
#pragma unroll
    for (int k = 0; k < 2; ++k)
#pragma unroll
    for (int j = 0; j < 2; ++j)
#pragma unroll
    for (int i = 0; i < 2; ++i) {
        const bool v = s.vx[i] && s.vy[j] && s.vz[k];
        uint32_t idx = (hx[i] ^ hy[j] ^ hz[k]) & HMASK;
        idx = v ? idx : 0u;
        const float w = v ? (s.wx[i]*s.wy[j]*s.wz[k]) : 0.0f;
        const float2 e = tab[idx];
        ax = fmaf(e.x, w, ax);
        ay = fmaf(e.y, w, ay);
    }
    return make_float2(ax, ay);
}

// ---------------- binning ----------------
__device__ __forceinline__ uint32_t part1by2(uint32_t v)
{
    v = (v | (v << 16)) & 0x030000FFu;
    v = (v | (v << 8))  & 0x0300F00Fu;
    v = (v | (v << 4))  & 0x030C30C3u;
    v = (v | (v << 2))  & 0x09249249u;
    return v;
}

__device__ __forceinline__ uint32_t bin_of(float x, float y, float z)
{
    const int bx = min(max((int)((x + 1.0f) * 16.0f), 0), 31);
    const int by = min(max((int)((y + 1.0f) * 16.0f), 0), 31);
    const int bz = min(max((int)((z + 1.0f) * 16.0f), 0), 31);
    return part1by2((uint32_t)bx) | (part1by2((uint32_t)by) << 1) | (part1by2((uint32_t)bz) << 2);
}

__global__ __launch_bounds__(BLOCK) void hist_kernel(
    const float* __restrict__ x, uint32_t* __restrict__ hist, int n)
{
    const int b = blockIdx.x * BLOCK + threadIdx.x;
    if (b >= n) return;
    atomicAdd(&hist[bin_of(x[3*b+0], x[3*b+1], x[3*b+2])], 1u);
}

__global__ __launch_bounds__(1024) void scan_kernel(
    const uint32_t* __restrict__ hist, uint32_t* __restrict__ cursor)
{
    __shared__ uint32_t tot[1024];
    const int t = threadIdx.x;
    uint32_t v[32];
    uint32_t s = 0;
#pragma unroll
    for (int i = 0; i < 32; ++i) { v[i] = s; s += hist[t*32 + i]; }  // local exclusive
    tot[t] = s;
    __syncthreads();
    for (int off = 1; off < 1024; off <<= 1) {
        const uint32_t y = (t >= off) ? tot[t - off] : 0u;
        __syncthreads();
        tot[t] += y;
        __syncthreads();
    }
    const uint32_t base = tot[t] - s;   // exclusive
#pragma unroll
    for (int i = 0; i < 32; ++i) cursor[t*32 + i] = base + v[i];
}

__global__ __launch_bounds__(BLOCK) void scatter_kernel(
    const float* __restrict__ x, uint32_t* __restrict__ cursor,
    float4* __restrict__ xs, int n)
{
    const int b = blockIdx.x * BLOCK + threadIdx.x;
    if (b >= n) return;
    const float px = x[3*b+0], py = x[3*b+1], pz = x[3*b+2];
    const uint32_t pos = atomicAdd(&cursor[bin_of(px, py, pz)], 1u);
    xs[pos] = make_float4(px, py, pz, __int_as_float(b));
}

// ---- Dense levels 0-7, BIN ORDER: L0,L1 from LDS; lower 64B scattered ----
__global__ __launch_bounds__(DBLOCK) void dense_kernel_binned(
    const float4* __restrict__ xs, EmbPtrs embs, float4* __restrict__ out, int n)
{
    __shared__ float2 lds0[L0N];
    __shared__ float2 lds1[L1N];
    {
        const float4* g0 = (const float4*)embs.p[0];
        const float4* g1 = (const float4*)embs.p[1];
        float4* s0 = (float4*)lds0;
        float4* s1 = (float4*)lds1;
#pragma unroll 2
        for (int i = threadIdx.x; i < L0N/2; i += DBLOCK) s0[i] = g0[i];
#pragma unroll 4
        for (int i = threadIdx.x; i < L1N/2; i += DBLOCK) s1[i] = g1[i];
    }
    __syncthreads();

    const int i = blockIdx.x * DBLOCK + threadIdx.x;
    if (i >= n) return;
    const float4 q = xs[i];                       // coalesced
    const float px = q.x, py = q.y, pz = q.z;
    const int idx = __float_as_int(q.w);

    float2 f[8];
    f[0] = dense_feat<16>((const float2*)lds0, px, py, pz);
    f[1] = dense_feat<20>((const float2*)lds1, px, py, pz);
    f[2] = dense_feat<25>(embs.p[2], px, py, pz);
    f[3] = dense_feat<32>(embs.p[3], px, py, pz);
    f[4] = dense_feat<40>(embs.p[4], px, py, pz);
    f[5] = dense_feat<50>(embs.p[5], px, py, pz);
    f[6] = dense_feat<64>(embs.p[6], px, py, pz);
    f[7] = dense_feat<80>(embs.p[7], px, py, pz);

    float4* o = out + (size_t)idx * 8;            // scattered, full 64B sector
#pragma unroll
    for (int k = 0; k < 4; ++k)
        o[k] = make_float4(f[2*k].x, f[2*k].y, f[2*k+1].x, f[2*k+1].y);
}

// ---- ALL 8 hash levels, BIN ORDER, fused; upper 64B scattered direct ----
__global__ __launch_bounds__(BLOCK) void hash_all_kernel(
    const float4* __restrict__ xs, EmbPtrs embs, float4* __restrict__ out, int n)
{
    const int i = blockIdx.x * BLOCK + threadIdx.x;
    if (i >= n) return;
    const float4 q = xs[i];                       // coalesced
    const float px = q.x, py = q.y, pz = q.z;
    const int idx = __float_as_int(q.w);

    float2 f[8];
    f[0] = hash_feat<101>(embs.p[8],  px, py, pz);
    f[1] = hash_feat<128>(embs.p[9],  px, py, pz);
    f[2] = hash_feat<161>(embs.p[10], px, py, pz);
    f[3] = hash_feat<203>(embs.p[11], px, py, pz);
    f[4] = hash_feat<256>(embs.p[12], px, py, pz);
    f[5] = hash_feat<322>(embs.p[13], px, py, pz);
    f[6] = hash_feat<406>(embs.p[14], px, py, pz);
    f[7] = hash_feat<512>(embs.p[15], px, py, pz);

    float4* o = out + (size_t)idx * 8 + 4;        // scattered, full 64B sector
#pragma unroll
    for (int k = 0; k < 4; ++k)
        o[k] = make_float4(f[2*k].x, f[2*k].y, f[2*k+1].x, f[2*k+1].y);
}

// ---- Fallback if d_ws too small: single fused kernel, original order ----
__global__ __launch_bounds__(BLOCK) void fallback_kernel(
    const float* __restrict__ x, EmbPtrs embs, float4* __restrict__ out, int n)
{
    const int b = blockIdx.x * BLOCK + threadIdx.x;
    if (b >= n) return;
    const float px = x[3*b+0], py = x[3*b+1], pz = x[3*b+2];
    float2 f[16];
    f[0]  = dense_feat<16 >(embs.p[0],  px, py, pz);
    f[1]  = dense_feat<20 >(embs.p[1],  px, py, pz);
    f[2]  = dense_feat<25 >(embs.p[2],  px, py, pz);
    f[3]  = dense_feat<32 >(embs.p[3],  px, py, pz);
    f[4]  = dense_feat<40 >(embs.p[4],  px, py, pz);
    f[5]  = dense_feat<50 >(embs.p[5],  px, py, pz);
    f[6]  = dense_feat<64 >(embs.p[6],  px, py, pz);
    f[7]  = dense_feat<80 >(embs.p[7],  px, py, pz);
    f[8]  = hash_feat<101>(embs.p[8],  px, py, pz);
    f[9]  = hash_feat<128>(embs.p[9],  px, py, pz);
    f[10] = hash_feat<161>(embs.p[10], px, py, pz);
    f[11] = hash_feat<203>(embs.p[11], px, py, pz);
    f[12] = hash_feat<256>(embs.p[12], px, py, pz);
    f[13] = hash_feat<322>(embs.p[13], px, py, pz);
    f[14] = hash_feat<406>(embs.p[14], px, py, pz);
    f[15] = hash_feat<512>(embs.p[15], px, py, pz);
    float4* o = out + (size_t)b * 8;
#pragma unroll
    for (int i = 0; i < 8; ++i)
        o[i] = make_float4(f[2*i].x, f[2*i].y, f[2*i+1].x, f[2*i+1].y);
}

extern "C" void kernel_launch(void* const* d_in, const int* in_sizes, int n_in,
                              void* d_out, int out_size, void* d_ws, size_t ws_size,
                              hipStream_t stream) {
    const float* x = (const float*)d_in[0];
    EmbPtrs embs;
    for (int l = 0; l < 16; ++l) embs.p[l] = (const float2*)d_in[1 + l];
    const int n = in_sizes[0] / 3;          // (B,3) fp32
    const int grid  = (n + BLOCK - 1) / BLOCK;
    const int dgrid = (n + DBLOCK - 1) / DBLOCK;
    float4* out = (float4*)d_out;

    // ws layout: [xs n*16B][hist 128KB][cursor 128KB]  (~16.5 MB @ n=1M)
    const size_t xsB   = (size_t)n * sizeof(float4);
    const size_t histB = (size_t)NBINS * sizeof(uint32_t);
    const size_t need  = xsB + 2 * histB;

    if (ws_size >= need) {
        float4*   xs     = (float4*)d_ws;
        uint32_t* hist   = (uint32_t*)((char*)d_ws + xsB);
        uint32_t* cursor = hist + NBINS;

        hipMemsetAsync(hist, 0, histB, stream);
        hist_kernel<<<grid, BLOCK, 0, stream>>>(x, hist, n);
        scan_kernel<<<1, 1024, 0, stream>>>(hist, cursor);
        scatter_kernel<<<grid, BLOCK, 0, stream>>>(x, cursor, xs, n);

        dense_kernel_binned<<<dgrid, DBLOCK, 0, stream>>>(xs, embs, out, n);
        hash_all_kernel<<<grid, BLOCK, 0, stream>>>(xs, embs, out, n);
    } else {
        fallback_kernel<<<grid, BLOCK, 0, stream>>>(x, embs, out, n);
    }
}